// Round 2
// baseline (1043.381 us; speedup 1.0000x reference)
//
#include <hip/hip_runtime.h>
#include <math.h>

// ---------------------------------------------------------------------------
// LiDARPriorQueryGenerator — MI355X (gfx950). FP32 I/O per reference dtypes.
// prep(w-reorder+bf16, bn-fold) -> NCHW f32 -> NHWC bf16 (W padded to 130)
// -> conv1 MFMA (bf16, gll16) -> featb bf16 -> conv2 MFMA + fused 1x1 score
// (atomicAdd logits) -> approx top-128 -> EXACT fp32 rescore from original
// inputs -> final top-100 -> fused FFN/LN/heads/anchor (fp32 out).
// ---------------------------------------------------------------------------

typedef __attribute__((ext_vector_type(8))) short bf16x8;
typedef __attribute__((ext_vector_type(4))) float f32x4;

#define HW 16384
#define WPITCH 130   // padded width: col 0 and 129 are zero pads
// workspace byte offsets
#define WSO_XN    0ULL           // bf16 NHWC padded input  (34,078,720)
#define WSO_FEATB 34078720ULL    // bf16 NHWC padded feat   (34,078,720)
#define WSO_WP1   68157440ULL    // bf16 [9][256][256] shared_w
#define WSO_WP2   69337088ULL    // bf16 [9][256][256] obj_w1
#define WSO_BNP   70516736ULL    // fp32 scale1,shift1,scale2,shift2,w2f (1280)
#define WSO_LOG   70521856ULL    // fp32 65536 logits
#define WSO_CAND  70784000ULL    // int 4*128
#define WSO_EXL   70786048ULL    // fp32 4*128
#define WSO_TIDX  70788096ULL    // int 4*100
#define WSO_TLOG  70789696ULL    // fp32 4*100

__device__ __forceinline__ float bf2f(short s) {
  return __uint_as_float(((unsigned)(unsigned short)s) << 16);
}
__device__ __forceinline__ short f2bf(float f) {  // RNE
  unsigned u = __float_as_uint(f);
  u += 0x7fffu + ((u >> 16) & 1u);
  return (short)(u >> 16);
}
__device__ __forceinline__ void gll16(const void* g, void* l) {
  __builtin_amdgcn_global_load_lds(
      (const __attribute__((address_space(1))) void*)g,
      (__attribute__((address_space(3))) void*)l, 16, 0, 0);
}

// --- prep: reorder conv weights (co,ci,kh,kw) f32 -> [tap][co][ci] bf16 -----
__global__ void wreorder(const float* __restrict__ src, short* __restrict__ dst) {
  int i = blockIdx.x * 256 + threadIdx.x;  // grid 2304
  int ci = i & 255;
  int r = i >> 8;
  int co = r & 255;
  int tap = r >> 8;
  dst[i] = f2bf(src[(co * 256 + ci) * 9 + tap]);
}

// --- prep: fold BN into scale/shift (fp32-exact), copy w2 -------------------
__global__ void bnprep(const float* g1, const float* b1, const float* m1,
                       const float* v1, const float* g2, const float* b2,
                       const float* m2, const float* v2, const float* w2,
                       float* __restrict__ out) {
  int c = threadIdx.x;
  float s1 = g1[c] / sqrtf(v1[c] + 1e-5f);
  out[c] = s1;
  out[256 + c] = b1[c] - m1[c] * s1;
  float s2 = g2[c] / sqrtf(v2[c] + 1e-5f);
  out[512 + c] = s2;
  out[768 + c] = b2[c] - m2[c] * s2;
  out[1024 + c] = w2[c];
}

// --- zero the W-pad columns of xn and featb ---------------------------------
__global__ void padzero(short* __restrict__ xn, short* __restrict__ featb) {
  int i = blockIdx.x * 256 + threadIdx.x;  // grid 1024 -> 262144
  int c = i & 255;
  int r = i >> 8;            // 0..1023 : nh(512) x side(2)
  int nh = r >> 1;
  int side = r & 1;
  size_t off = ((size_t)nh * WPITCH + (side ? 129 : 0)) * 256 + c;
  xn[off] = 0;
  featb[off] = 0;
}

// --- logits init to 1x1 bias ------------------------------------------------
__global__ void loginit(float* __restrict__ logits, const float* __restrict__ b2) {
  logits[blockIdx.x * 256 + threadIdx.x] = b2[0];
}

// --- NCHW f32 -> NHWC bf16 (padded W) ---------------------------------------
__global__ __launch_bounds__(256) void nchw2nhwc(const float* __restrict__ in,
                                                 short* __restrict__ out) {
  __shared__ short tl[64 * 66];
  int n = blockIdx.z, c0 = blockIdx.y * 64, s0 = blockIdx.x * 64;
  int sl = threadIdx.x & 63, cl = threadIdx.x >> 6;
  for (int p = 0; p < 16; ++p) {
    int c = cl + p * 4;
    tl[c * 66 + sl] = f2bf(in[(((size_t)(n * 256 + c0 + c)) << 14) + s0 + sl]);
  }
  __syncthreads();
  int co = threadIdx.x & 63, so = threadIdx.x >> 6;
  for (int p = 0; p < 16; ++p) {
    int S = s0 + so + p * 4;
    int h = S >> 7, w = S & 127;
    out[(((size_t)(n * 128 + h)) * WPITCH + w + 1) * 256 + c0 + co] =
        tl[co * 66 + (so + p * 4)];
  }
}

// --- 3x3 conv + BN + ReLU via MFMA; OUT_LOGITS fuses the 1x1 score ----------
template <int OUT_LOGITS>
__global__ __launch_bounds__(256) void conv3x3(const short* __restrict__ inp,
                                               const short* __restrict__ wp,
                                               const float* __restrict__ scale,
                                               const float* __restrict__ shift,
                                               const float* __restrict__ w2f,
                                               short* __restrict__ outb,
                                               float* __restrict__ logits) {
  __shared__ short a_sm[128 * 32];
  __shared__ short b_sm[128 * 32];
  const int t = threadIdx.x;
  const int wv = t >> 6, lane = t & 63;
  const int l15 = lane & 15, quad = lane >> 4;
  const int tile = blockIdx.x;
  const int img = tile >> 7;
  const int h = tile & 127;
  const int nblk = blockIdx.y;
  const int m0 = (wv & 1) << 6;
  const int n0 = (wv >> 1) << 6;

  f32x4 acc[4][4];
#pragma unroll
  for (int i = 0; i < 4; ++i)
#pragma unroll
    for (int j = 0; j < 4; ++j) {
      acc[i][j][0] = 0.f; acc[i][j][1] = 0.f;
      acc[i][j][2] = 0.f; acc[i][j][3] = 0.f;
    }

  for (int tap = 0; tap < 9; ++tap) {
    const int dh = tap / 3 - 1, dw = tap % 3 - 1;
    const int hy = h + dh;
    if (hy < 0 || hy > 127) continue;  // block-uniform row-pad skip
    const size_t arow = ((size_t)(img * 128 + hy)) * WPITCH;
    const short* wtap = wp + ((size_t)(tap * 256 + nblk * 128)) * 256;

    for (int c0 = 0; c0 < 256; c0 += 32) {
      __syncthreads();
      // stage A: rows = w (padded cols make all lanes in-bounds: full exec)
#pragma unroll
      for (int j = 0; j < 2; ++j) {
        const int mrow = (j << 6) + (t >> 2);
        const int cc = t & 3;
        gll16(inp + (arow + mrow + dw + 1) * 256 + c0 + cc * 8,
              a_sm + ((size_t)((j << 8) + t)) * 8);
      }
      // stage B: rows = co
#pragma unroll
      for (int j = 0; j < 2; ++j) {
        const int nrow = (j << 6) + (t >> 2);
        const int cc = t & 3;
        gll16(wtap + (size_t)nrow * 256 + c0 + cc * 8,
              b_sm + ((size_t)((j << 8) + t)) * 8);
      }
      __syncthreads();  // vmcnt(0) drain lands the LDS writes

      bf16x8 af[4], bfr[4];
#pragma unroll
      for (int i = 0; i < 4; ++i)
        af[i] = *(const bf16x8*)(a_sm + (m0 + i * 16 + l15) * 32 + quad * 8);
#pragma unroll
      for (int i = 0; i < 4; ++i)
        bfr[i] = *(const bf16x8*)(b_sm + (n0 + i * 16 + l15) * 32 + quad * 8);
#pragma unroll
      for (int i = 0; i < 4; ++i)
#pragma unroll
        for (int j = 0; j < 4; ++j)
          acc[i][j] = __builtin_amdgcn_mfma_f32_16x16x32_bf16(af[i], bfr[j],
                                                              acc[i][j], 0, 0, 0);
    }
  }

  // C/D map: col = lane&15, row = quad*4 + reg
  float sc[4], sh[4], wf[4];
#pragma unroll
  for (int j = 0; j < 4; ++j) {
    const int co = nblk * 128 + n0 + j * 16 + l15;
    sc[j] = scale[co];
    sh[j] = shift[co];
    if (OUT_LOGITS) wf[j] = w2f[co];
  }
  if (OUT_LOGITS) {
    float* lrow = logits + ((size_t)img << 14) + (h << 7);
#pragma unroll
    for (int i = 0; i < 4; ++i) {
#pragma unroll
      for (int r = 0; r < 4; ++r) {
        float part = 0.f;
#pragma unroll
        for (int j = 0; j < 4; ++j) {
          float v = fmaxf(acc[i][j][r] * sc[j] + sh[j], 0.f);
          part += v * wf[j];
        }
        part += __shfl_xor(part, 1);
        part += __shfl_xor(part, 2);
        part += __shfl_xor(part, 4);
        part += __shfl_xor(part, 8);
        if (l15 == 0)
          atomicAdd(&lrow[m0 + i * 16 + quad * 4 + r], part);
      }
    }
  } else {
    const size_t obase = ((size_t)(img * 128 + h)) * WPITCH + 1;
#pragma unroll
    for (int i = 0; i < 4; ++i) {
#pragma unroll
      for (int j = 0; j < 4; ++j) {
        const int co = nblk * 128 + n0 + j * 16 + l15;
#pragma unroll
        for (int r = 0; r < 4; ++r) {
          const int m = m0 + i * 16 + quad * 4 + r;
          float v = fmaxf(acc[i][j][r] * sc[j] + sh[j], 0.f);
          outb[(obase + m) * 256 + co] = f2bf(v);
        }
      }
    }
  }
}

// --- approx top-128 per batch -----------------------------------------------
__global__ __launch_bounds__(1024) void topk_approx(const float* __restrict__ logits,
                                                    int* __restrict__ cand) {
  __shared__ unsigned taken[512];
  __shared__ float wmax[16];
  __shared__ int widx[16];
  __shared__ int winner;
  const int b = blockIdx.x, t = threadIdx.x;
  const int lane = t & 63, wid = t >> 6;
  const float* L = logits + (size_t)b * HW;
  if (t < 512) taken[t] = 0u;
  const int base = t * 16;
  float lv[16];
#pragma unroll
  for (int i = 0; i < 4; ++i) {
    float4 v = *(const float4*)(L + base + i * 4);
    lv[i * 4 + 0] = v.x; lv[i * 4 + 1] = v.y;
    lv[i * 4 + 2] = v.z; lv[i * 4 + 3] = v.w;
  }
  __syncthreads();
  float lm = -3.0e38f;
  int li = 0x7FFFFFFF;
#pragma unroll
  for (int i = 0; i < 16; ++i)
    if (lv[i] > lm) { lm = lv[i]; li = base + i; }

  for (int r = 0; r < 128; ++r) {
    float mv = lm;
    int mi = li;
    for (int off = 32; off; off >>= 1) {
      float ov = __shfl_xor(mv, off);
      int oi = __shfl_xor(mi, off);
      if (ov > mv || (ov == mv && oi < mi)) { mv = ov; mi = oi; }
    }
    if (lane == 0) { wmax[wid] = mv; widx[wid] = mi; }
    __syncthreads();
    if (t == 0) {
      float bv = wmax[0];
      int bi = widx[0];
      for (int w = 1; w < 16; ++w)
        if (wmax[w] > bv || (wmax[w] == bv && widx[w] < bi)) {
          bv = wmax[w]; bi = widx[w];
        }
      cand[b * 128 + r] = bi;
      taken[bi >> 5] |= 1u << (bi & 31);
      winner = bi;
    }
    __syncthreads();
    if ((winner >> 4) == t) {  // owner rescans its 16 values
      unsigned tk = taken[base >> 5] >> (base & 16);
      lm = -3.0e38f;
      li = 0x7FFFFFFF;
#pragma unroll
      for (int i = 0; i < 16; ++i)
        if (!((tk >> i) & 1u) && lv[i] > lm) { lm = lv[i]; li = base + i; }
    }
  }
}

// --- EXACT fp32 rescore from original NCHW input + fp32 weights -------------
// logit(s) = 1x1( relu(bn2( conv2( relu(bn1( conv1(x) )) ))) )[s], all fp32.
__global__ __launch_bounds__(256) void rescore(const float* __restrict__ x,
                                               const float* __restrict__ w1,
                                               const float* __restrict__ ow1,
                                               const float* __restrict__ bnp,
                                               const float* __restrict__ b2,
                                               const int* __restrict__ cand,
                                               float* __restrict__ exlog) {
  const int c = blockIdx.x, b = blockIdx.y, t = threadIdx.x;
  __shared__ float xp_sm[25 * 256];   // 5x5 patch  [p][ci]
  __shared__ float f9_sm[9 * 256];    // 3x3 feats  [p9][ci]
  __shared__ float red[4];
  const int s = cand[b * 128 + c];
  const int h0 = s >> 7, w0 = s & 127;
#pragma unroll
  for (int p = 0; p < 25; ++p) {
    int hy = h0 + p / 5 - 2, wx = w0 + p % 5 - 2;
    float v = 0.f;
    if (hy >= 0 && hy < 128 && wx >= 0 && wx < 128)
      v = x[(((size_t)(b * 256 + t)) << 14) + (hy << 7) + wx];
    xp_sm[p * 256 + t] = v;
  }
  __syncthreads();
  // thread t computes feat[co=t] at the 9 neighbor positions
  float a9[9];
#pragma unroll
  for (int p = 0; p < 9; ++p) a9[p] = 0.f;
  for (int ci = 0; ci < 256; ++ci) {
    float w9[9];
    const float* wr = w1 + ((size_t)t * 256 + ci) * 9;
#pragma unroll
    for (int k = 0; k < 9; ++k) w9[k] = wr[k];
    float xp[25];
#pragma unroll
    for (int p = 0; p < 25; ++p) xp[p] = xp_sm[p * 256 + ci];
#pragma unroll
    for (int py = 0; py < 3; ++py)
#pragma unroll
      for (int px = 0; px < 3; ++px) {
#pragma unroll
        for (int ky = 0; ky < 3; ++ky)
#pragma unroll
          for (int kx = 0; kx < 3; ++kx)
            a9[py * 3 + px] += w9[ky * 3 + kx] * xp[(py + ky) * 5 + px + kx];
      }
  }
  {
    const float sc1 = bnp[t], sh1 = bnp[256 + t];
#pragma unroll
    for (int p = 0; p < 9; ++p)
      f9_sm[p * 256 + t] = fmaxf(a9[p] * sc1 + sh1, 0.f);
  }
  __syncthreads();
  // conv2 at s: thread t = co2
  float acc = 0.f;
  for (int ci = 0; ci < 256; ++ci) {
    const float* wr = ow1 + ((size_t)t * 256 + ci) * 9;
#pragma unroll
    for (int k = 0; k < 9; ++k) acc += wr[k] * f9_sm[k * 256 + ci];
  }
  float hv = fmaxf(acc * bnp[512 + t] + bnp[768 + t], 0.f);
  float p = hv * bnp[1024 + t];
  for (int off = 32; off; off >>= 1) p += __shfl_xor(p, off);
  if ((t & 63) == 0) red[t >> 6] = p;
  __syncthreads();
  if (t == 0) exlog[b * 128 + c] = red[0] + red[1] + red[2] + red[3] + b2[0];
}

// --- rank-sort 128 exact logits, keep top-100 (jax tie-break: lower idx) ----
__global__ __launch_bounds__(128) void final_topk(const float* __restrict__ exlog,
                                                  const int* __restrict__ cand,
                                                  int* __restrict__ tidx,
                                                  float* __restrict__ tlog) {
  const int b = blockIdx.x, t = threadIdx.x;
  __shared__ float v[128];
  __shared__ int si[128];
  float mv = exlog[b * 128 + t];
  int s = cand[b * 128 + t];
  v[t] = mv;
  si[t] = s;
  __syncthreads();
  int rank = 0;
  for (int j = 0; j < 128; ++j) {
    float vj = v[j];
    int sj = si[j];
    if (vj > mv || (vj == mv && sj < s)) ++rank;
  }
  if (rank < 100) {
    tidx[b * 100 + rank] = s;
    tlog[b * 100 + rank] = mv;
  }
}

// --- fused FFN + LN + heads + anchor (fp32 out), one block per query --------
__global__ __launch_bounds__(256) void head_kern(
    const short* __restrict__ featb, const int* __restrict__ tidx,
    const float* __restrict__ tlog, const float* __restrict__ tmpl,
    const float* __restrict__ w1, const float* __restrict__ b1,
    const float* __restrict__ lng, const float* __restrict__ lnb,
    const float* __restrict__ w2, const float* __restrict__ b2,
    const float* __restrict__ zw, const float* __restrict__ zb,
    const float* __restrict__ dmw, const float* __restrict__ dmb,
    const float* __restrict__ yw, const float* __restrict__ yb,
    const float* __restrict__ vw, const float* __restrict__ vb,
    float* __restrict__ out) {
  const int blk = blockIdx.x;  // 400
  const int b = blk / 100, q = blk % 100;
  const int t = threadIdx.x;
  const int lane = t & 63, wid = t >> 6;
  __shared__ float g[256];
  __shared__ float sx[256];
  __shared__ float red[4];
  __shared__ float heads[8];

  const int s = tidx[b * 100 + q];
  const float score = 1.f / (1.f + expf(-tlog[b * 100 + q]));
  const int ys = s >> 7, xs = s & 127;

  g[t] = bf2f(featb[(((size_t)(b * 128 + ys)) * WPITCH + xs + 1) * 256 + t]);
  __syncthreads();

  // x = g @ fp_w1.T + b1
  float x = b1[t];
  {
    const float* wr = w1 + (size_t)t * 256;
    for (int i = 0; i < 256; i += 4) {
      float4 wv = *(const float4*)(wr + i);
      x += g[i] * wv.x + g[i + 1] * wv.y + g[i + 2] * wv.z + g[i + 3] * wv.w;
    }
  }
  // LayerNorm (two-pass fp32)
  float sum = x;
  for (int off = 32; off; off >>= 1) sum += __shfl_xor(sum, off);
  if (lane == 0) red[wid] = sum;
  __syncthreads();
  float mu = (red[0] + red[1] + red[2] + red[3]) * (1.f / 256.f);
  __syncthreads();
  float d = x - mu;
  float q2 = d * d;
  for (int off = 32; off; off >>= 1) q2 += __shfl_xor(q2, off);
  if (lane == 0) red[wid] = q2;
  __syncthreads();
  float var = (red[0] + red[1] + red[2] + red[3]) * (1.f / 256.f);
  float xn = d * (1.f / sqrtf(var + 1e-5f)) * lng[t] + lnb[t];
  xn = fmaxf(xn, 0.f);
  sx[t] = xn;
  __syncthreads();
  float pf = b2[t];
  {
    const float* wr = w2 + (size_t)t * 256;
    for (int i = 0; i < 256; i += 4) {
      float4 wv = *(const float4*)(wr + i);
      pf += sx[i] * wv.x + sx[i + 1] * wv.y + sx[i + 2] * wv.z + sx[i + 3] * wv.w;
    }
  }
  pf *= (1.f + score);
  out[(size_t)(b * 100 + q) * 256 + t] = pf;

  // 8 head dots, 32 threads each
  const int k = t >> 5, l = t & 31;
  const float* hw;
  float hb;
  if (k == 0)      { hw = zw;                 hb = zb[0]; }
  else if (k < 4)  { hw = dmw + (k - 1) * 256; hb = dmb[k - 1]; }
  else if (k < 6)  { hw = yw + (k - 4) * 256;  hb = yb[k - 4]; }
  else             { hw = vw + (k - 6) * 256;  hb = vb[k - 6]; }
  float hp = 0.f;
#pragma unroll
  for (int r = 0; r < 8; ++r) {
    int i = l + r * 32;
    hp += g[i] * hw[i];
  }
  for (int off = 16; off; off >>= 1) hp += __shfl_xor(hp, off);
  if (l == 0) heads[k] = hp + hb;
  __syncthreads();

  if (t == 0) {
    const float* pa = tmpl + ((size_t)b * 900 + q) * 11;
    float p[11];
#pragma unroll
    for (int i = 0; i < 11; ++i) p[i] = pa[i];
    float a[11];
    a[0] = ((float)xs + 0.5f) * 0.8f - 51.2f;
    a[1] = ((float)ys + 0.5f) * 0.8f - 51.2f;
    a[2] = p[2] + 0.5f * heads[0];
#pragma unroll
    for (int i = 0; i < 3; ++i)
      a[3 + i] = p[3 + i] + 0.2f * fminf(fmaxf(heads[1 + i], -1.f), 1.f);
    float t0 = tanhf(heads[4]), t1 = tanhf(heads[5]);
    float nrm = fmaxf(sqrtf(t0 * t0 + t1 * t1), 1e-6f);
    a[6] = 0.7f * p[6] + 0.3f * t0 / nrm;
    a[7] = 0.7f * p[7] + 0.3f * t1 / nrm;
    a[8] = p[8] + 0.2f * fminf(fmaxf(heads[6], -2.f), 2.f);
    a[9] = p[9] + 0.2f * fminf(fmaxf(heads[7], -2.f), 2.f);
    a[10] = p[10];
    float* oa = out + 102400 + (size_t)(b * 100 + q) * 11;
#pragma unroll
    for (int i = 0; i < 11; ++i) oa[i] = a[i];
    out[106800 + b * 100 + q] = score;
  }
}

extern "C" void kernel_launch(void* const* d_in, const int* in_sizes, int n_in,
                              void* d_out, int out_size, void* d_ws, size_t ws_size,
                              hipStream_t stream) {
  (void)in_sizes; (void)n_in; (void)out_size; (void)ws_size;
  char* ws = (char*)d_ws;
  short* xn     = (short*)(ws + WSO_XN);
  short* featb  = (short*)(ws + WSO_FEATB);
  short* wp1    = (short*)(ws + WSO_WP1);
  short* wp2    = (short*)(ws + WSO_WP2);
  float* bnp    = (float*)(ws + WSO_BNP);
  float* logits = (float*)(ws + WSO_LOG);
  int*   cand   = (int*)(ws + WSO_CAND);
  float* exl    = (float*)(ws + WSO_EXL);
  int*   tidx   = (int*)(ws + WSO_TIDX);
  float* tlog   = (float*)(ws + WSO_TLOG);

  const float* bev = (const float*)d_in[0];

  wreorder<<<2304, 256, 0, stream>>>((const float*)d_in[2], wp1);
  wreorder<<<2304, 256, 0, stream>>>((const float*)d_in[7], wp2);
  bnprep<<<1, 256, 0, stream>>>(
      (const float*)d_in[3], (const float*)d_in[4], (const float*)d_in[5],
      (const float*)d_in[6], (const float*)d_in[8], (const float*)d_in[9],
      (const float*)d_in[10], (const float*)d_in[11], (const float*)d_in[12], bnp);
  padzero<<<1024, 256, 0, stream>>>(xn, featb);
  loginit<<<256, 256, 0, stream>>>(logits, (const float*)d_in[13]);
  nchw2nhwc<<<dim3(256, 4, 4), 256, 0, stream>>>(bev, xn);
  conv3x3<0><<<dim3(512, 2), 256, 0, stream>>>(xn, wp1, bnp, bnp + 256,
                                               nullptr, featb, nullptr);
  conv3x3<1><<<dim3(512, 2), 256, 0, stream>>>(featb, wp2, bnp + 512, bnp + 768,
                                               bnp + 1024, nullptr, logits);
  topk_approx<<<4, 1024, 0, stream>>>(logits, cand);
  rescore<<<dim3(128, 4), 256, 0, stream>>>(bev, (const float*)d_in[2],
                                            (const float*)d_in[7], bnp,
                                            (const float*)d_in[13], cand, exl);
  final_topk<<<4, 128, 0, stream>>>(exl, cand, tidx, tlog);
  head_kern<<<400, 256, 0, stream>>>(
      featb, tidx, tlog, (const float*)d_in[1],
      (const float*)d_in[14], (const float*)d_in[15], (const float*)d_in[16],
      (const float*)d_in[17], (const float*)d_in[18], (const float*)d_in[19],
      (const float*)d_in[20], (const float*)d_in[21], (const float*)d_in[22],
      (const float*)d_in[23], (const float*)d_in[24], (const float*)d_in[25],
      (const float*)d_in[26], (const float*)d_in[27], (float*)d_out);
}

// Round 3
// 913.442 us; speedup vs baseline: 1.1423x; 1.1423x over previous
//
#include <hip/hip_runtime.h>
#include <math.h>

// ---------------------------------------------------------------------------
// LiDARPriorQueryGenerator — MI355X (gfx950). FP32 I/O per reference dtypes.
// prep(w-reorder bf16 + fp32 transpose, bn-fold) -> NHWC bf16 (W padded 130)
// -> conv1 MFMA -> featb bf16 -> conv2 MFMA + fused 1x1 score (atomicAdd
// logits) -> approx top-128 -> EXACT fp32 rescore (coalesced [tap][ci][co]
// weights) -> final top-100 -> fused FFN/LN/heads/anchor (fp32 out).
// ---------------------------------------------------------------------------

typedef __attribute__((ext_vector_type(8))) short bf16x8;
typedef __attribute__((ext_vector_type(4))) float f32x4;

#define HW 16384
#define WPITCH 130   // padded width: col 0 and 129 are zero pads
// workspace byte offsets
#define WSO_XN    0ULL           // bf16 NHWC padded input  (34,078,720)
#define WSO_FEATB 34078720ULL    // bf16 NHWC padded feat   (34,078,720)
#define WSO_WP1   68157440ULL    // bf16 [9][256][256] shared_w
#define WSO_WP2   69337088ULL    // bf16 [9][256][256] obj_w1
#define WSO_BNP   70516736ULL    // fp32 scale1,shift1,scale2,shift2,w2f (1280)
#define WSO_LOG   70521856ULL    // fp32 65536 logits
#define WSO_CAND  70784000ULL    // int 4*128
#define WSO_EXL   70786048ULL    // fp32 4*128
#define WSO_TIDX  70788096ULL    // int 4*100
#define WSO_TLOG  70789696ULL    // fp32 4*100
#define WSO_W1T   70791296ULL    // fp32 [tap][ci][co] shared_w (2,359,296)
#define WSO_W2T   73150592ULL    // fp32 [tap][ci][co] obj_w1   (2,359,296)

__device__ __forceinline__ float bf2f(short s) {
  return __uint_as_float(((unsigned)(unsigned short)s) << 16);
}
__device__ __forceinline__ short f2bf(float f) {  // RNE
  unsigned u = __float_as_uint(f);
  u += 0x7fffu + ((u >> 16) & 1u);
  return (short)(u >> 16);
}
__device__ __forceinline__ void gll16(const void* g, void* l) {
  __builtin_amdgcn_global_load_lds(
      (const __attribute__((address_space(1))) void*)g,
      (__attribute__((address_space(3))) void*)l, 16, 0, 0);
}

// --- prep: reorder conv weights (co,ci,kh,kw) f32 -> [tap][co][ci] bf16 -----
__global__ void wreorder(const float* __restrict__ src, short* __restrict__ dst) {
  int i = blockIdx.x * 256 + threadIdx.x;  // grid 2304
  int ci = i & 255;
  int r = i >> 8;
  int co = r & 255;
  int tap = r >> 8;
  dst[i] = f2bf(src[(co * 256 + ci) * 9 + tap]);
}

// --- prep: transpose conv weights f32 -> [tap][ci][co] fp32 (for rescore) ---
__global__ void wtrans(const float* __restrict__ src, float* __restrict__ dst) {
  int i = blockIdx.x * 256 + threadIdx.x;  // grid 2304
  int co = i & 255;
  int r = i >> 8;
  int ci = r & 255;
  int tap = r >> 8;
  dst[i] = src[(co * 256 + ci) * 9 + tap];
}

// --- prep: fold BN into scale/shift (fp32-exact), copy w2 -------------------
__global__ void bnprep(const float* g1, const float* b1, const float* m1,
                       const float* v1, const float* g2, const float* b2,
                       const float* m2, const float* v2, const float* w2,
                       float* __restrict__ out) {
  int c = threadIdx.x;
  float s1 = g1[c] / sqrtf(v1[c] + 1e-5f);
  out[c] = s1;
  out[256 + c] = b1[c] - m1[c] * s1;
  float s2 = g2[c] / sqrtf(v2[c] + 1e-5f);
  out[512 + c] = s2;
  out[768 + c] = b2[c] - m2[c] * s2;
  out[1024 + c] = w2[c];
}

// --- zero the W-pad columns of xn and featb ---------------------------------
__global__ void padzero(short* __restrict__ xn, short* __restrict__ featb) {
  int i = blockIdx.x * 256 + threadIdx.x;  // grid 1024 -> 262144
  int c = i & 255;
  int r = i >> 8;            // 0..1023 : nh(512) x side(2)
  int nh = r >> 1;
  int side = r & 1;
  size_t off = ((size_t)nh * WPITCH + (side ? 129 : 0)) * 256 + c;
  xn[off] = 0;
  featb[off] = 0;
}

// --- logits init to 1x1 bias ------------------------------------------------
__global__ void loginit(float* __restrict__ logits, const float* __restrict__ b2) {
  logits[blockIdx.x * 256 + threadIdx.x] = b2[0];
}

// --- NCHW f32 -> NHWC bf16 (padded W) ---------------------------------------
__global__ __launch_bounds__(256) void nchw2nhwc(const float* __restrict__ in,
                                                 short* __restrict__ out) {
  __shared__ short tl[64 * 66];
  int n = blockIdx.z, c0 = blockIdx.y * 64, s0 = blockIdx.x * 64;
  int sl = threadIdx.x & 63, cl = threadIdx.x >> 6;
  for (int p = 0; p < 16; ++p) {
    int c = cl + p * 4;
    tl[c * 66 + sl] = f2bf(in[(((size_t)(n * 256 + c0 + c)) << 14) + s0 + sl]);
  }
  __syncthreads();
  int co = threadIdx.x & 63, so = threadIdx.x >> 6;
  for (int p = 0; p < 16; ++p) {
    int S = s0 + so + p * 4;
    int h = S >> 7, w = S & 127;
    out[(((size_t)(n * 128 + h)) * WPITCH + w + 1) * 256 + c0 + co] =
        tl[co * 66 + (so + p * 4)];
  }
}

// --- 3x3 conv + BN + ReLU via MFMA; OUT_LOGITS fuses the 1x1 score ----------
template <int OUT_LOGITS>
__global__ __launch_bounds__(256) void conv3x3(const short* __restrict__ inp,
                                               const short* __restrict__ wp,
                                               const float* __restrict__ scale,
                                               const float* __restrict__ shift,
                                               const float* __restrict__ w2f,
                                               short* __restrict__ outb,
                                               float* __restrict__ logits) {
  __shared__ short a_sm[128 * 32];
  __shared__ short b_sm[128 * 32];
  const int t = threadIdx.x;
  const int wv = t >> 6, lane = t & 63;
  const int l15 = lane & 15, quad = lane >> 4;
  const int tile = blockIdx.x;
  const int img = tile >> 7;
  const int h = tile & 127;
  const int nblk = blockIdx.y;
  const int m0 = (wv & 1) << 6;
  const int n0 = (wv >> 1) << 6;

  f32x4 acc[4][4];
#pragma unroll
  for (int i = 0; i < 4; ++i)
#pragma unroll
    for (int j = 0; j < 4; ++j) {
      acc[i][j][0] = 0.f; acc[i][j][1] = 0.f;
      acc[i][j][2] = 0.f; acc[i][j][3] = 0.f;
    }

  for (int tap = 0; tap < 9; ++tap) {
    const int dh = tap / 3 - 1, dw = tap % 3 - 1;
    const int hy = h + dh;
    if (hy < 0 || hy > 127) continue;  // block-uniform row-pad skip
    const size_t arow = ((size_t)(img * 128 + hy)) * WPITCH;
    const short* wtap = wp + ((size_t)(tap * 256 + nblk * 128)) * 256;

    for (int c0 = 0; c0 < 256; c0 += 32) {
      __syncthreads();
      // stage A: rows = w (padded cols make all lanes in-bounds: full exec)
#pragma unroll
      for (int j = 0; j < 2; ++j) {
        const int mrow = (j << 6) + (t >> 2);
        const int cc = t & 3;
        gll16(inp + (arow + mrow + dw + 1) * 256 + c0 + cc * 8,
              a_sm + ((size_t)((j << 8) + t)) * 8);
      }
      // stage B: rows = co
#pragma unroll
      for (int j = 0; j < 2; ++j) {
        const int nrow = (j << 6) + (t >> 2);
        const int cc = t & 3;
        gll16(wtap + (size_t)nrow * 256 + c0 + cc * 8,
              b_sm + ((size_t)((j << 8) + t)) * 8);
      }
      __syncthreads();  // vmcnt(0) drain lands the LDS writes

      bf16x8 af[4], bfr[4];
#pragma unroll
      for (int i = 0; i < 4; ++i)
        af[i] = *(const bf16x8*)(a_sm + (m0 + i * 16 + l15) * 32 + quad * 8);
#pragma unroll
      for (int i = 0; i < 4; ++i)
        bfr[i] = *(const bf16x8*)(b_sm + (n0 + i * 16 + l15) * 32 + quad * 8);
#pragma unroll
      for (int i = 0; i < 4; ++i)
#pragma unroll
        for (int j = 0; j < 4; ++j)
          acc[i][j] = __builtin_amdgcn_mfma_f32_16x16x32_bf16(af[i], bfr[j],
                                                              acc[i][j], 0, 0, 0);
    }
  }

  // C/D map: col = lane&15, row = quad*4 + reg
  float sc[4], sh[4], wf[4];
#pragma unroll
  for (int j = 0; j < 4; ++j) {
    const int co = nblk * 128 + n0 + j * 16 + l15;
    sc[j] = scale[co];
    sh[j] = shift[co];
    if (OUT_LOGITS) wf[j] = w2f[co];
  }
  if (OUT_LOGITS) {
    float* lrow = logits + ((size_t)img << 14) + (h << 7);
#pragma unroll
    for (int i = 0; i < 4; ++i) {
#pragma unroll
      for (int r = 0; r < 4; ++r) {
        float part = 0.f;
#pragma unroll
        for (int j = 0; j < 4; ++j) {
          float v = fmaxf(acc[i][j][r] * sc[j] + sh[j], 0.f);
          part += v * wf[j];
        }
        part += __shfl_xor(part, 1);
        part += __shfl_xor(part, 2);
        part += __shfl_xor(part, 4);
        part += __shfl_xor(part, 8);
        if (l15 == 0)
          atomicAdd(&lrow[m0 + i * 16 + quad * 4 + r], part);
      }
    }
  } else {
    const size_t obase = ((size_t)(img * 128 + h)) * WPITCH + 1;
#pragma unroll
    for (int i = 0; i < 4; ++i) {
#pragma unroll
      for (int j = 0; j < 4; ++j) {
        const int co = nblk * 128 + n0 + j * 16 + l15;
#pragma unroll
        for (int r = 0; r < 4; ++r) {
          const int m = m0 + i * 16 + quad * 4 + r;
          float v = fmaxf(acc[i][j][r] * sc[j] + sh[j], 0.f);
          outb[(obase + m) * 256 + co] = f2bf(v);
        }
      }
    }
  }
}

// --- approx top-128 per batch -----------------------------------------------
__global__ __launch_bounds__(1024) void topk_approx(const float* __restrict__ logits,
                                                    int* __restrict__ cand) {
  __shared__ unsigned taken[512];
  __shared__ float wmax[16];
  __shared__ int widx[16];
  __shared__ int winner;
  const int b = blockIdx.x, t = threadIdx.x;
  const int lane = t & 63, wid = t >> 6;
  const float* L = logits + (size_t)b * HW;
  if (t < 512) taken[t] = 0u;
  const int base = t * 16;
  float lv[16];
#pragma unroll
  for (int i = 0; i < 4; ++i) {
    float4 v = *(const float4*)(L + base + i * 4);
    lv[i * 4 + 0] = v.x; lv[i * 4 + 1] = v.y;
    lv[i * 4 + 2] = v.z; lv[i * 4 + 3] = v.w;
  }
  __syncthreads();
  float lm = -3.0e38f;
  int li = 0x7FFFFFFF;
#pragma unroll
  for (int i = 0; i < 16; ++i)
    if (lv[i] > lm) { lm = lv[i]; li = base + i; }

  for (int r = 0; r < 128; ++r) {
    float mv = lm;
    int mi = li;
    for (int off = 32; off; off >>= 1) {
      float ov = __shfl_xor(mv, off);
      int oi = __shfl_xor(mi, off);
      if (ov > mv || (ov == mv && oi < mi)) { mv = ov; mi = oi; }
    }
    if (lane == 0) { wmax[wid] = mv; widx[wid] = mi; }
    __syncthreads();
    if (t == 0) {
      float bv = wmax[0];
      int bi = widx[0];
      for (int w = 1; w < 16; ++w)
        if (wmax[w] > bv || (wmax[w] == bv && widx[w] < bi)) {
          bv = wmax[w]; bi = widx[w];
        }
      cand[b * 128 + r] = bi;
      taken[bi >> 5] |= 1u << (bi & 31);
      winner = bi;
    }
    __syncthreads();
    if ((winner >> 4) == t) {  // owner rescans its 16 values
      unsigned tk = taken[base >> 5] >> (base & 16);
      lm = -3.0e38f;
      li = 0x7FFFFFFF;
#pragma unroll
      for (int i = 0; i < 16; ++i)
        if (!((tk >> i) & 1u) && lv[i] > lm) { lm = lv[i]; li = base + i; }
    }
  }
}

// --- EXACT fp32 rescore, coalesced [tap][ci][co] weights --------------------
// logit(s) = 1x1( relu(bn2( conv2( relu(bn1( conv1(x) )) ))) )[s], all fp32.
__global__ __launch_bounds__(256) void rescore(const float* __restrict__ x,
                                               const float* __restrict__ w1t,
                                               const float* __restrict__ w2t,
                                               const float* __restrict__ bnp,
                                               const float* __restrict__ b2,
                                               const int* __restrict__ cand,
                                               float* __restrict__ exlog) {
  const int c = blockIdx.x, b = blockIdx.y, t = threadIdx.x;
  __shared__ float xp_sm[256 * 28];  // [ci][28]: 5x5 patch, b128-aligned pad
  __shared__ float f9_sm[256 * 12];  // [ci][12]: 3x3 feats
  __shared__ float red[4];
  const int s = cand[b * 128 + c];
  const int h0 = s >> 7, w0 = s & 127;
  // stage: thread t loads channel t's 5x5 patch (25 small loads, one-time)
  {
    const float* xc = x + (((size_t)(b * 256 + t)) << 14);
#pragma unroll
    for (int p = 0; p < 25; ++p) {
      int hy = h0 + p / 5 - 2, wx = w0 + p % 5 - 2;
      float v = 0.f;
      if (hy >= 0 && hy < 128 && wx >= 0 && wx < 128) v = xc[(hy << 7) + wx];
      xp_sm[t * 28 + p] = v;
    }
  }
  __syncthreads();
  // conv1: thread t = co computes 9 output positions; weights coalesced,
  // patch reads are same-address lane-broadcast b128s (free).
  float a9[9];
#pragma unroll
  for (int p = 0; p < 9; ++p) a9[p] = 0.f;
  for (int ci = 0; ci < 256; ++ci) {
    float w9[9];
    const float* wr = w1t + (size_t)ci * 256 + t;
#pragma unroll
    for (int k = 0; k < 9; ++k) w9[k] = wr[(size_t)k * 65536];
    float xp[25];
    const float4* xr = (const float4*)(xp_sm + ci * 28);
#pragma unroll
    for (int q = 0; q < 6; ++q) {
      float4 v = xr[q];
      xp[q * 4 + 0] = v.x; xp[q * 4 + 1] = v.y;
      xp[q * 4 + 2] = v.z; xp[q * 4 + 3] = v.w;
    }
    xp[24] = xp_sm[ci * 28 + 24];
#pragma unroll
    for (int py = 0; py < 3; ++py)
#pragma unroll
      for (int px = 0; px < 3; ++px)
#pragma unroll
        for (int ky = 0; ky < 3; ++ky)
#pragma unroll
          for (int kx = 0; kx < 3; ++kx)
            a9[py * 3 + px] += w9[ky * 3 + kx] * xp[(py + ky) * 5 + px + kx];
  }
  {
    const float sc1 = bnp[t], sh1 = bnp[256 + t];
#pragma unroll
    for (int p = 0; p < 9; ++p)
      f9_sm[t * 12 + p] = fmaxf(a9[p] * sc1 + sh1, 0.f);
  }
  __syncthreads();
  // conv2 at s: thread t = co2; weights coalesced, feats broadcast
  float acc = 0.f;
  for (int ci = 0; ci < 256; ++ci) {
    const float* wr = w2t + (size_t)ci * 256 + t;
    float f9[12];
    const float4* fr = (const float4*)(f9_sm + ci * 12);
#pragma unroll
    for (int q = 0; q < 3; ++q) {
      float4 v = fr[q];
      f9[q * 4 + 0] = v.x; f9[q * 4 + 1] = v.y;
      f9[q * 4 + 2] = v.z; f9[q * 4 + 3] = v.w;
    }
#pragma unroll
    for (int k = 0; k < 9; ++k) acc += wr[(size_t)k * 65536] * f9[k];
  }
  float hv = fmaxf(acc * bnp[512 + t] + bnp[768 + t], 0.f);
  float p = hv * bnp[1024 + t];
  for (int off = 32; off; off >>= 1) p += __shfl_xor(p, off);
  if ((t & 63) == 0) red[t >> 6] = p;
  __syncthreads();
  if (t == 0) exlog[b * 128 + c] = red[0] + red[1] + red[2] + red[3] + b2[0];
}

// --- rank-sort 128 exact logits, keep top-100 (jax tie-break: lower idx) ----
__global__ __launch_bounds__(128) void final_topk(const float* __restrict__ exlog,
                                                  const int* __restrict__ cand,
                                                  int* __restrict__ tidx,
                                                  float* __restrict__ tlog) {
  const int b = blockIdx.x, t = threadIdx.x;
  __shared__ float v[128];
  __shared__ int si[128];
  float mv = exlog[b * 128 + t];
  int s = cand[b * 128 + t];
  v[t] = mv;
  si[t] = s;
  __syncthreads();
  int rank = 0;
  for (int j = 0; j < 128; ++j) {
    float vj = v[j];
    int sj = si[j];
    if (vj > mv || (vj == mv && sj < s)) ++rank;
  }
  if (rank < 100) {
    tidx[b * 100 + rank] = s;
    tlog[b * 100 + rank] = mv;
  }
}

// --- fused FFN + LN + heads + anchor (fp32 out), one block per query --------
__global__ __launch_bounds__(256) void head_kern(
    const short* __restrict__ featb, const int* __restrict__ tidx,
    const float* __restrict__ tlog, const float* __restrict__ tmpl,
    const float* __restrict__ w1, const float* __restrict__ b1,
    const float* __restrict__ lng, const float* __restrict__ lnb,
    const float* __restrict__ w2, const float* __restrict__ b2,
    const float* __restrict__ zw, const float* __restrict__ zb,
    const float* __restrict__ dmw, const float* __restrict__ dmb,
    const float* __restrict__ yw, const float* __restrict__ yb,
    const float* __restrict__ vw, const float* __restrict__ vb,
    float* __restrict__ out) {
  const int blk = blockIdx.x;  // 400
  const int b = blk / 100, q = blk % 100;
  const int t = threadIdx.x;
  const int lane = t & 63, wid = t >> 6;
  __shared__ float g[256];
  __shared__ float sx[256];
  __shared__ float red[4];
  __shared__ float heads[8];

  const int s = tidx[b * 100 + q];
  const float score = 1.f / (1.f + expf(-tlog[b * 100 + q]));
  const int ys = s >> 7, xs = s & 127;

  g[t] = bf2f(featb[(((size_t)(b * 128 + ys)) * WPITCH + xs + 1) * 256 + t]);
  __syncthreads();

  // x = g @ fp_w1.T + b1
  float x = b1[t];
  {
    const float* wr = w1 + (size_t)t * 256;
    for (int i = 0; i < 256; i += 4) {
      float4 wv = *(const float4*)(wr + i);
      x += g[i] * wv.x + g[i + 1] * wv.y + g[i + 2] * wv.z + g[i + 3] * wv.w;
    }
  }
  // LayerNorm (two-pass fp32)
  float sum = x;
  for (int off = 32; off; off >>= 1) sum += __shfl_xor(sum, off);
  if (lane == 0) red[wid] = sum;
  __syncthreads();
  float mu = (red[0] + red[1] + red[2] + red[3]) * (1.f / 256.f);
  __syncthreads();
  float d = x - mu;
  float q2 = d * d;
  for (int off = 32; off; off >>= 1) q2 += __shfl_xor(q2, off);
  if (lane == 0) red[wid] = q2;
  __syncthreads();
  float var = (red[0] + red[1] + red[2] + red[3]) * (1.f / 256.f);
  float xn = d * (1.f / sqrtf(var + 1e-5f)) * lng[t] + lnb[t];
  xn = fmaxf(xn, 0.f);
  sx[t] = xn;
  __syncthreads();
  float pf = b2[t];
  {
    const float* wr = w2 + (size_t)t * 256;
    for (int i = 0; i < 256; i += 4) {
      float4 wv = *(const float4*)(wr + i);
      pf += sx[i] * wv.x + sx[i + 1] * wv.y + sx[i + 2] * wv.z + sx[i + 3] * wv.w;
    }
  }
  pf *= (1.f + score);
  out[(size_t)(b * 100 + q) * 256 + t] = pf;

  // 8 head dots, 32 threads each
  const int k = t >> 5, l = t & 31;
  const float* hw;
  float hb;
  if (k == 0)      { hw = zw;                 hb = zb[0]; }
  else if (k < 4)  { hw = dmw + (k - 1) * 256; hb = dmb[k - 1]; }
  else if (k < 6)  { hw = yw + (k - 4) * 256;  hb = yb[k - 4]; }
  else             { hw = vw + (k - 6) * 256;  hb = vb[k - 6]; }
  float hp = 0.f;
#pragma unroll
  for (int r = 0; r < 8; ++r) {
    int i = l + r * 32;
    hp += g[i] * hw[i];
  }
  for (int off = 16; off; off >>= 1) hp += __shfl_xor(hp, off);
  if (l == 0) heads[k] = hp + hb;
  __syncthreads();

  if (t == 0) {
    const float* pa = tmpl + ((size_t)b * 900 + q) * 11;
    float p[11];
#pragma unroll
    for (int i = 0; i < 11; ++i) p[i] = pa[i];
    float a[11];
    a[0] = ((float)xs + 0.5f) * 0.8f - 51.2f;
    a[1] = ((float)ys + 0.5f) * 0.8f - 51.2f;
    a[2] = p[2] + 0.5f * heads[0];
#pragma unroll
    for (int i = 0; i < 3; ++i)
      a[3 + i] = p[3 + i] + 0.2f * fminf(fmaxf(heads[1 + i], -1.f), 1.f);
    float t0 = tanhf(heads[4]), t1 = tanhf(heads[5]);
    float nrm = fmaxf(sqrtf(t0 * t0 + t1 * t1), 1e-6f);
    a[6] = 0.7f * p[6] + 0.3f * t0 / nrm;
    a[7] = 0.7f * p[7] + 0.3f * t1 / nrm;
    a[8] = p[8] + 0.2f * fminf(fmaxf(heads[6], -2.f), 2.f);
    a[9] = p[9] + 0.2f * fminf(fmaxf(heads[7], -2.f), 2.f);
    a[10] = p[10];
    float* oa = out + 102400 + (size_t)(b * 100 + q) * 11;
#pragma unroll
    for (int i = 0; i < 11; ++i) oa[i] = a[i];
    out[106800 + b * 100 + q] = score;
  }
}

extern "C" void kernel_launch(void* const* d_in, const int* in_sizes, int n_in,
                              void* d_out, int out_size, void* d_ws, size_t ws_size,
                              hipStream_t stream) {
  (void)in_sizes; (void)n_in; (void)out_size; (void)ws_size;
  char* ws = (char*)d_ws;
  short* xn     = (short*)(ws + WSO_XN);
  short* featb  = (short*)(ws + WSO_FEATB);
  short* wp1    = (short*)(ws + WSO_WP1);
  short* wp2    = (short*)(ws + WSO_WP2);
  float* bnp    = (float*)(ws + WSO_BNP);
  float* logits = (float*)(ws + WSO_LOG);
  int*   cand   = (int*)(ws + WSO_CAND);
  float* exl    = (float*)(ws + WSO_EXL);
  int*   tidx   = (int*)(ws + WSO_TIDX);
  float* tlog   = (float*)(ws + WSO_TLOG);
  float* w1t    = (float*)(ws + WSO_W1T);
  float* w2t    = (float*)(ws + WSO_W2T);

  const float* bev = (const float*)d_in[0];

  wreorder<<<2304, 256, 0, stream>>>((const float*)d_in[2], wp1);
  wreorder<<<2304, 256, 0, stream>>>((const float*)d_in[7], wp2);
  wtrans<<<2304, 256, 0, stream>>>((const float*)d_in[2], w1t);
  wtrans<<<2304, 256, 0, stream>>>((const float*)d_in[7], w2t);
  bnprep<<<1, 256, 0, stream>>>(
      (const float*)d_in[3], (const float*)d_in[4], (const float*)d_in[5],
      (const float*)d_in[6], (const float*)d_in[8], (const float*)d_in[9],
      (const float*)d_in[10], (const float*)d_in[11], (const float*)d_in[12], bnp);
  padzero<<<1024, 256, 0, stream>>>(xn, featb);
  loginit<<<256, 256, 0, stream>>>(logits, (const float*)d_in[13]);
  nchw2nhwc<<<dim3(256, 4, 4), 256, 0, stream>>>(bev, xn);
  conv3x3<0><<<dim3(512, 2), 256, 0, stream>>>(xn, wp1, bnp, bnp + 256,
                                               nullptr, featb, nullptr);
  conv3x3<1><<<dim3(512, 2), 256, 0, stream>>>(featb, wp2, bnp + 512, bnp + 768,
                                               bnp + 1024, nullptr, logits);
  topk_approx<<<4, 1024, 0, stream>>>(logits, cand);
  rescore<<<dim3(128, 4), 256, 0, stream>>>(bev, w1t, w2t, bnp,
                                            (const float*)d_in[13], cand, exl);
  final_topk<<<4, 128, 0, stream>>>(exl, cand, tidx, tlog);
  head_kern<<<400, 256, 0, stream>>>(
      featb, tidx, tlog, (const float*)d_in[1],
      (const float*)d_in[14], (const float*)d_in[15], (const float*)d_in[16],
      (const float*)d_in[17], (const float*)d_in[18], (const float*)d_in[19],
      (const float*)d_in[20], (const float*)d_in[21], (const float*)d_in[22],
      (const float*)d_in[23], (const float*)d_in[24], (const float*)d_in[25],
      (const float*)d_in[26], (const float*)d_in[27], (float*)d_out);
}

// Round 4
// 656.776 us; speedup vs baseline: 1.5886x; 1.3908x over previous
//
#include <hip/hip_runtime.h>
#include <math.h>

// ---------------------------------------------------------------------------
// LiDARPriorQueryGenerator — MI355X (gfx950). FP32 I/O per reference dtypes.
// prep(w-reorder bf16 + fp32 transpose, bn-fold) -> NHWC bf16 (W padded 130)
// -> conv1 MFMA -> featb bf16 -> conv2 MFMA + fused 1x1 score (atomicAdd
// logits) -> RADIX-SELECT top>=128 -> EXACT fp32 rescore (coalesced
// [tap][ci][co] weights) -> final top-100 -> fused FFN/LN/heads/anchor.
// ---------------------------------------------------------------------------

typedef __attribute__((ext_vector_type(8))) short bf16x8;
typedef __attribute__((ext_vector_type(4))) float f32x4;

#define HW 16384
#define WPITCH 130   // padded width: col 0 and 129 are zero pads
#define CCAP 192     // candidate cap (count(key>=K*) typically 128..~132)
// workspace byte offsets
#define WSO_XN    0ULL           // bf16 NHWC padded input  (34,078,720)
#define WSO_FEATB 34078720ULL    // bf16 NHWC padded feat   (34,078,720)
#define WSO_WP1   68157440ULL    // bf16 [9][256][256] shared_w
#define WSO_WP2   69337088ULL    // bf16 [9][256][256] obj_w1
#define WSO_BNP   70516736ULL    // fp32 scale1,shift1,scale2,shift2,w2f (1280)
#define WSO_LOG   70521856ULL    // fp32 65536 logits
#define WSO_CAND  70784000ULL    // int 4*CCAP
#define WSO_CNT   70787072ULL    // int 4 (+pad)
#define WSO_EXL   70787136ULL    // fp32 4*CCAP
#define WSO_TIDX  70790208ULL    // int 4*100
#define WSO_TLOG  70791808ULL    // fp32 4*100
#define WSO_W1T   70793408ULL    // fp32 [tap][ci][co] shared_w (2,359,296)
#define WSO_W2T   73152704ULL    // fp32 [tap][ci][co] obj_w1   (2,359,296)

__device__ __forceinline__ float bf2f(short s) {
  return __uint_as_float(((unsigned)(unsigned short)s) << 16);
}
__device__ __forceinline__ short f2bf(float f) {  // RNE
  unsigned u = __float_as_uint(f);
  u += 0x7fffu + ((u >> 16) & 1u);
  return (short)(u >> 16);
}
__device__ __forceinline__ void gll16(const void* g, void* l) {
  __builtin_amdgcn_global_load_lds(
      (const __attribute__((address_space(1))) void*)g,
      (__attribute__((address_space(3))) void*)l, 16, 0, 0);
}

// --- prep: reorder conv weights (co,ci,kh,kw) f32 -> [tap][co][ci] bf16 -----
__global__ void wreorder(const float* __restrict__ src, short* __restrict__ dst) {
  int i = blockIdx.x * 256 + threadIdx.x;  // grid 2304
  int ci = i & 255;
  int r = i >> 8;
  int co = r & 255;
  int tap = r >> 8;
  dst[i] = f2bf(src[(co * 256 + ci) * 9 + tap]);
}

// --- prep: transpose conv weights f32 -> [tap][ci][co] fp32 (for rescore) ---
__global__ void wtrans(const float* __restrict__ src, float* __restrict__ dst) {
  int i = blockIdx.x * 256 + threadIdx.x;  // grid 2304
  int co = i & 255;
  int r = i >> 8;
  int ci = r & 255;
  int tap = r >> 8;
  dst[i] = src[(co * 256 + ci) * 9 + tap];
}

// --- prep: fold BN into scale/shift (fp32-exact), copy w2 -------------------
__global__ void bnprep(const float* g1, const float* b1, const float* m1,
                       const float* v1, const float* g2, const float* b2,
                       const float* m2, const float* v2, const float* w2,
                       float* __restrict__ out) {
  int c = threadIdx.x;
  float s1 = g1[c] / sqrtf(v1[c] + 1e-5f);
  out[c] = s1;
  out[256 + c] = b1[c] - m1[c] * s1;
  float s2 = g2[c] / sqrtf(v2[c] + 1e-5f);
  out[512 + c] = s2;
  out[768 + c] = b2[c] - m2[c] * s2;
  out[1024 + c] = w2[c];
}

// --- zero the W-pad columns of xn and featb ---------------------------------
__global__ void padzero(short* __restrict__ xn, short* __restrict__ featb) {
  int i = blockIdx.x * 256 + threadIdx.x;  // grid 1024 -> 262144
  int c = i & 255;
  int r = i >> 8;            // 0..1023 : nh(512) x side(2)
  int nh = r >> 1;
  int side = r & 1;
  size_t off = ((size_t)nh * WPITCH + (side ? 129 : 0)) * 256 + c;
  xn[off] = 0;
  featb[off] = 0;
}

// --- logits init to 1x1 bias ------------------------------------------------
__global__ void loginit(float* __restrict__ logits, const float* __restrict__ b2) {
  logits[blockIdx.x * 256 + threadIdx.x] = b2[0];
}

// --- NCHW f32 -> NHWC bf16 (padded W) ---------------------------------------
__global__ __launch_bounds__(256) void nchw2nhwc(const float* __restrict__ in,
                                                 short* __restrict__ out) {
  __shared__ short tl[64 * 66];
  int n = blockIdx.z, c0 = blockIdx.y * 64, s0 = blockIdx.x * 64;
  int sl = threadIdx.x & 63, cl = threadIdx.x >> 6;
  for (int p = 0; p < 16; ++p) {
    int c = cl + p * 4;
    tl[c * 66 + sl] = f2bf(in[(((size_t)(n * 256 + c0 + c)) << 14) + s0 + sl]);
  }
  __syncthreads();
  int co = threadIdx.x & 63, so = threadIdx.x >> 6;
  for (int p = 0; p < 16; ++p) {
    int S = s0 + so + p * 4;
    int h = S >> 7, w = S & 127;
    out[(((size_t)(n * 128 + h)) * WPITCH + w + 1) * 256 + c0 + co] =
        tl[co * 66 + (so + p * 4)];
  }
}

// --- 3x3 conv + BN + ReLU via MFMA; OUT_LOGITS fuses the 1x1 score ----------
template <int OUT_LOGITS>
__global__ __launch_bounds__(256) void conv3x3(const short* __restrict__ inp,
                                               const short* __restrict__ wp,
                                               const float* __restrict__ scale,
                                               const float* __restrict__ shift,
                                               const float* __restrict__ w2f,
                                               short* __restrict__ outb,
                                               float* __restrict__ logits) {
  __shared__ short a_sm[128 * 32];
  __shared__ short b_sm[128 * 32];
  const int t = threadIdx.x;
  const int wv = t >> 6, lane = t & 63;
  const int l15 = lane & 15, quad = lane >> 4;
  const int tile = blockIdx.x;
  const int img = tile >> 7;
  const int h = tile & 127;
  const int nblk = blockIdx.y;
  const int m0 = (wv & 1) << 6;
  const int n0 = (wv >> 1) << 6;

  f32x4 acc[4][4];
#pragma unroll
  for (int i = 0; i < 4; ++i)
#pragma unroll
    for (int j = 0; j < 4; ++j) {
      acc[i][j][0] = 0.f; acc[i][j][1] = 0.f;
      acc[i][j][2] = 0.f; acc[i][j][3] = 0.f;
    }

  for (int tap = 0; tap < 9; ++tap) {
    const int dh = tap / 3 - 1, dw = tap % 3 - 1;
    const int hy = h + dh;
    if (hy < 0 || hy > 127) continue;  // block-uniform row-pad skip
    const size_t arow = ((size_t)(img * 128 + hy)) * WPITCH;
    const short* wtap = wp + ((size_t)(tap * 256 + nblk * 128)) * 256;

    for (int c0 = 0; c0 < 256; c0 += 32) {
      __syncthreads();
      // stage A: rows = w (padded cols make all lanes in-bounds: full exec)
#pragma unroll
      for (int j = 0; j < 2; ++j) {
        const int mrow = (j << 6) + (t >> 2);
        const int cc = t & 3;
        gll16(inp + (arow + mrow + dw + 1) * 256 + c0 + cc * 8,
              a_sm + ((size_t)((j << 8) + t)) * 8);
      }
      // stage B: rows = co
#pragma unroll
      for (int j = 0; j < 2; ++j) {
        const int nrow = (j << 6) + (t >> 2);
        const int cc = t & 3;
        gll16(wtap + (size_t)nrow * 256 + c0 + cc * 8,
              b_sm + ((size_t)((j << 8) + t)) * 8);
      }
      __syncthreads();  // vmcnt(0) drain lands the LDS writes

      bf16x8 af[4], bfr[4];
#pragma unroll
      for (int i = 0; i < 4; ++i)
        af[i] = *(const bf16x8*)(a_sm + (m0 + i * 16 + l15) * 32 + quad * 8);
#pragma unroll
      for (int i = 0; i < 4; ++i)
        bfr[i] = *(const bf16x8*)(b_sm + (n0 + i * 16 + l15) * 32 + quad * 8);
#pragma unroll
      for (int i = 0; i < 4; ++i)
#pragma unroll
        for (int j = 0; j < 4; ++j)
          acc[i][j] = __builtin_amdgcn_mfma_f32_16x16x32_bf16(af[i], bfr[j],
                                                              acc[i][j], 0, 0, 0);
    }
  }

  // C/D map: col = lane&15, row = quad*4 + reg
  float sc[4], sh[4], wf[4];
#pragma unroll
  for (int j = 0; j < 4; ++j) {
    const int co = nblk * 128 + n0 + j * 16 + l15;
    sc[j] = scale[co];
    sh[j] = shift[co];
    if (OUT_LOGITS) wf[j] = w2f[co];
  }
  if (OUT_LOGITS) {
    float* lrow = logits + ((size_t)img << 14) + (h << 7);
#pragma unroll
    for (int i = 0; i < 4; ++i) {
#pragma unroll
      for (int r = 0; r < 4; ++r) {
        float part = 0.f;
#pragma unroll
        for (int j = 0; j < 4; ++j) {
          float v = fmaxf(acc[i][j][r] * sc[j] + sh[j], 0.f);
          part += v * wf[j];
        }
        part += __shfl_xor(part, 1);
        part += __shfl_xor(part, 2);
        part += __shfl_xor(part, 4);
        part += __shfl_xor(part, 8);
        if (l15 == 0)
          atomicAdd(&lrow[m0 + i * 16 + quad * 4 + r], part);
      }
    }
  } else {
    const size_t obase = ((size_t)(img * 128 + h)) * WPITCH + 1;
#pragma unroll
    for (int i = 0; i < 4; ++i) {
#pragma unroll
      for (int j = 0; j < 4; ++j) {
        const int co = nblk * 128 + n0 + j * 16 + l15;
#pragma unroll
        for (int r = 0; r < 4; ++r) {
          const int m = m0 + i * 16 + quad * 4 + r;
          float v = fmaxf(acc[i][j][r] * sc[j] + sh[j], 0.f);
          outb[(obase + m) * 256 + co] = f2bf(v);
        }
      }
    }
  }
}

// --- radix-select: all elements with key >= K*, where K* is the exact
// 32-bit key threshold of rank 128. One block per batch. ---------------------
__global__ __launch_bounds__(1024) void topk_radix(const float* __restrict__ logits,
                                                   int* __restrict__ cand,
                                                   int* __restrict__ cnt_out) {
  __shared__ int hist[2048];
  __shared__ int wsum[16];
  __shared__ unsigned sel_bin;
  __shared__ int sel_above;
  __shared__ int cntr;
  const int b = blockIdx.x, t = threadIdx.x;
  const int lane = t & 63, wid = t >> 6;
  const float* L = logits + (size_t)b * HW;
  const int base = t * 16;
  unsigned kv[16];
#pragma unroll
  for (int i = 0; i < 4; ++i) {
    float4 v = *(const float4*)(L + base + i * 4);
    float f4[4] = {v.x, v.y, v.z, v.w};
#pragma unroll
    for (int j = 0; j < 4; ++j) {
      unsigned u = __float_as_uint(f4[j]);
      kv[i * 4 + j] = u ^ (((unsigned)((int)u >> 31)) | 0x80000000u);
    }
  }
  unsigned prefix = 0, pmask = 0;
  int need = 128;
  const int shifts[3] = {21, 10, 0};
  const int nbs[3] = {2048, 2048, 1024};

  for (int lev = 0; lev < 3; ++lev) {
    const int shift = shifts[lev];
    const int nb = nbs[lev];
    hist[t] = 0;
    hist[t + 1024] = 0;
    __syncthreads();
#pragma unroll
    for (int i = 0; i < 16; ++i)
      if ((kv[i] & pmask) == prefix)
        atomicAdd(&hist[(kv[i] >> shift) & (nb - 1)], 1);
    __syncthreads();
    // descending chunk ownership: thread t owns bins [bin_hi-cs+1 .. bin_hi]
    const int cs = nb >> 10;  // 2 or 1
    const int bin_hi = nb - 1 - t * cs;
    const int c_hi = hist[bin_hi];
    const int c_lo = (cs == 2) ? hist[bin_hi - 1] : 0;
    const int s = c_hi + c_lo;
    // exclusive scan over thread order
    int inc = s;
    for (int off = 1; off < 64; off <<= 1) {
      int nbr = __shfl_up(inc, off);
      if (lane >= off) inc += nbr;
    }
    if (lane == 63) wsum[wid] = inc;
    __syncthreads();
    if (wid == 0) {
      int wv = (lane < 16) ? wsum[lane] : 0;
      for (int off = 1; off < 16; off <<= 1) {
        int nbr = __shfl_up(wv, off);
        if (lane >= off) wv += nbr;
      }
      if (lane < 16) wsum[lane] = wv;
    }
    __syncthreads();
    const int excl = inc - s + (wid ? wsum[wid - 1] : 0);
    if (excl < need && need <= excl + s) {  // exactly one thread
      if (need <= excl + c_hi) {
        sel_bin = (unsigned)bin_hi;
        sel_above = excl;
      } else {
        sel_bin = (unsigned)(bin_hi - 1);
        sel_above = excl + c_hi;
      }
    }
    __syncthreads();
    prefix |= sel_bin << shift;
    pmask |= ((unsigned)(nb - 1)) << shift;
    need -= sel_above;
    __syncthreads();
  }
  // prefix == K* (exact rank-128 key). Select key >= K* (>=128 elems).
  if (t == 0) cntr = 0;
  __syncthreads();
#pragma unroll
  for (int i = 0; i < 16; ++i) {
    if (kv[i] >= prefix) {
      int p = atomicAdd(&cntr, 1);
      if (p < CCAP) cand[b * CCAP + p] = base + i;
    }
  }
  __syncthreads();
  if (t == 0) cnt_out[b] = (cntr < CCAP) ? cntr : CCAP;
}

// --- EXACT fp32 rescore, coalesced [tap][ci][co] weights --------------------
// logit(s) = 1x1( relu(bn2( conv2( relu(bn1( conv1(x) )) ))) )[s], all fp32.
__global__ __launch_bounds__(256) void rescore(const float* __restrict__ x,
                                               const float* __restrict__ w1t,
                                               const float* __restrict__ w2t,
                                               const float* __restrict__ bnp,
                                               const float* __restrict__ b2,
                                               const int* __restrict__ cand,
                                               const int* __restrict__ cnt,
                                               float* __restrict__ exlog) {
  const int c = blockIdx.x, b = blockIdx.y, t = threadIdx.x;
  if (c >= cnt[b]) return;  // uniform early-exit, before any barrier
  __shared__ float xp_sm[256 * 28];  // [ci][28]: 5x5 patch, b128-aligned pad
  __shared__ float f9_sm[256 * 12];  // [ci][12]: 3x3 feats
  __shared__ float red[4];
  const int s = cand[b * CCAP + c];
  const int h0 = s >> 7, w0 = s & 127;
  {
    const float* xc = x + (((size_t)(b * 256 + t)) << 14);
#pragma unroll
    for (int p = 0; p < 25; ++p) {
      int hy = h0 + p / 5 - 2, wx = w0 + p % 5 - 2;
      float v = 0.f;
      if (hy >= 0 && hy < 128 && wx >= 0 && wx < 128) v = xc[(hy << 7) + wx];
      xp_sm[t * 28 + p] = v;
    }
  }
  __syncthreads();
  float a9[9];
#pragma unroll
  for (int p = 0; p < 9; ++p) a9[p] = 0.f;
  for (int ci = 0; ci < 256; ++ci) {
    float w9[9];
    const float* wr = w1t + (size_t)ci * 256 + t;
#pragma unroll
    for (int k = 0; k < 9; ++k) w9[k] = wr[(size_t)k * 65536];
    float xp[25];
    const float4* xr = (const float4*)(xp_sm + ci * 28);
#pragma unroll
    for (int q = 0; q < 6; ++q) {
      float4 v = xr[q];
      xp[q * 4 + 0] = v.x; xp[q * 4 + 1] = v.y;
      xp[q * 4 + 2] = v.z; xp[q * 4 + 3] = v.w;
    }
    xp[24] = xp_sm[ci * 28 + 24];
#pragma unroll
    for (int py = 0; py < 3; ++py)
#pragma unroll
      for (int px = 0; px < 3; ++px)
#pragma unroll
        for (int ky = 0; ky < 3; ++ky)
#pragma unroll
          for (int kx = 0; kx < 3; ++kx)
            a9[py * 3 + px] += w9[ky * 3 + kx] * xp[(py + ky) * 5 + px + kx];
  }
  {
    const float sc1 = bnp[t], sh1 = bnp[256 + t];
#pragma unroll
    for (int p = 0; p < 9; ++p)
      f9_sm[t * 12 + p] = fmaxf(a9[p] * sc1 + sh1, 0.f);
  }
  __syncthreads();
  float acc = 0.f;
  for (int ci = 0; ci < 256; ++ci) {
    const float* wr = w2t + (size_t)ci * 256 + t;
    float f9[12];
    const float4* fr = (const float4*)(f9_sm + ci * 12);
#pragma unroll
    for (int q = 0; q < 3; ++q) {
      float4 v = fr[q];
      f9[q * 4 + 0] = v.x; f9[q * 4 + 1] = v.y;
      f9[q * 4 + 2] = v.z; f9[q * 4 + 3] = v.w;
    }
#pragma unroll
    for (int k = 0; k < 9; ++k) acc += wr[(size_t)k * 65536] * f9[k];
  }
  float hv = fmaxf(acc * bnp[512 + t] + bnp[768 + t], 0.f);
  float p = hv * bnp[1024 + t];
  for (int off = 32; off; off >>= 1) p += __shfl_xor(p, off);
  if ((t & 63) == 0) red[t >> 6] = p;
  __syncthreads();
  if (t == 0) exlog[b * CCAP + c] = red[0] + red[1] + red[2] + red[3] + b2[0];
}

// --- rank-sort exact logits, keep top-100 (jax tie-break: lower idx) --------
__global__ __launch_bounds__(CCAP) void final_topk(const float* __restrict__ exlog,
                                                   const int* __restrict__ cand,
                                                   const int* __restrict__ cnt,
                                                   int* __restrict__ tidx,
                                                   float* __restrict__ tlog) {
  const int b = blockIdx.x, t = threadIdx.x;
  __shared__ float v[CCAP];
  __shared__ int si[CCAP];
  const int n = cnt[b];
  float mv = (t < n) ? exlog[b * CCAP + t] : -3.0e38f;
  int s = (t < n) ? cand[b * CCAP + t] : 0x7FFFFFFF;
  v[t] = mv;
  si[t] = s;
  __syncthreads();
  int rank = 0;
  for (int j = 0; j < CCAP; ++j) {
    float vj = v[j];
    int sj = si[j];
    if (vj > mv || (vj == mv && sj < s)) ++rank;
  }
  if (t < n && rank < 100) {
    tidx[b * 100 + rank] = s;
    tlog[b * 100 + rank] = mv;
  }
}

// --- fused FFN + LN + heads + anchor (fp32 out), one block per query --------
__global__ __launch_bounds__(256) void head_kern(
    const short* __restrict__ featb, const int* __restrict__ tidx,
    const float* __restrict__ tlog, const float* __restrict__ tmpl,
    const float* __restrict__ w1, const float* __restrict__ b1,
    const float* __restrict__ lng, const float* __restrict__ lnb,
    const float* __restrict__ w2, const float* __restrict__ b2,
    const float* __restrict__ zw, const float* __restrict__ zb,
    const float* __restrict__ dmw, const float* __restrict__ dmb,
    const float* __restrict__ yw, const float* __restrict__ yb,
    const float* __restrict__ vw, const float* __restrict__ vb,
    float* __restrict__ out) {
  const int blk = blockIdx.x;  // 400
  const int b = blk / 100, q = blk % 100;
  const int t = threadIdx.x;
  const int lane = t & 63, wid = t >> 6;
  __shared__ float g[256];
  __shared__ float sx[256];
  __shared__ float red[4];
  __shared__ float heads[8];

  const int s = tidx[b * 100 + q];
  const float score = 1.f / (1.f + expf(-tlog[b * 100 + q]));
  const int ys = s >> 7, xs = s & 127;

  g[t] = bf2f(featb[(((size_t)(b * 128 + ys)) * WPITCH + xs + 1) * 256 + t]);
  __syncthreads();

  float x = b1[t];
  {
    const float* wr = w1 + (size_t)t * 256;
    for (int i = 0; i < 256; i += 4) {
      float4 wv = *(const float4*)(wr + i);
      x += g[i] * wv.x + g[i + 1] * wv.y + g[i + 2] * wv.z + g[i + 3] * wv.w;
    }
  }
  float sum = x;
  for (int off = 32; off; off >>= 1) sum += __shfl_xor(sum, off);
  if (lane == 0) red[wid] = sum;
  __syncthreads();
  float mu = (red[0] + red[1] + red[2] + red[3]) * (1.f / 256.f);
  __syncthreads();
  float d = x - mu;
  float q2 = d * d;
  for (int off = 32; off; off >>= 1) q2 += __shfl_xor(q2, off);
  if (lane == 0) red[wid] = q2;
  __syncthreads();
  float var = (red[0] + red[1] + red[2] + red[3]) * (1.f / 256.f);
  float xn = d * (1.f / sqrtf(var + 1e-5f)) * lng[t] + lnb[t];
  xn = fmaxf(xn, 0.f);
  sx[t] = xn;
  __syncthreads();
  float pf = b2[t];
  {
    const float* wr = w2 + (size_t)t * 256;
    for (int i = 0; i < 256; i += 4) {
      float4 wv = *(const float4*)(wr + i);
      pf += sx[i] * wv.x + sx[i + 1] * wv.y + sx[i + 2] * wv.z + sx[i + 3] * wv.w;
    }
  }
  pf *= (1.f + score);
  out[(size_t)(b * 100 + q) * 256 + t] = pf;

  const int k = t >> 5, l = t & 31;
  const float* hw;
  float hb;
  if (k == 0)      { hw = zw;                 hb = zb[0]; }
  else if (k < 4)  { hw = dmw + (k - 1) * 256; hb = dmb[k - 1]; }
  else if (k < 6)  { hw = yw + (k - 4) * 256;  hb = yb[k - 4]; }
  else             { hw = vw + (k - 6) * 256;  hb = vb[k - 6]; }
  float hp = 0.f;
#pragma unroll
  for (int r = 0; r < 8; ++r) {
    int i = l + r * 32;
    hp += g[i] * hw[i];
  }
  for (int off = 16; off; off >>= 1) hp += __shfl_xor(hp, off);
  if (l == 0) heads[k] = hp + hb;
  __syncthreads();

  if (t == 0) {
    const float* pa = tmpl + ((size_t)b * 900 + q) * 11;
    float p[11];
#pragma unroll
    for (int i = 0; i < 11; ++i) p[i] = pa[i];
    float a[11];
    a[0] = ((float)xs + 0.5f) * 0.8f - 51.2f;
    a[1] = ((float)ys + 0.5f) * 0.8f - 51.2f;
    a[2] = p[2] + 0.5f * heads[0];
#pragma unroll
    for (int i = 0; i < 3; ++i)
      a[3 + i] = p[3 + i] + 0.2f * fminf(fmaxf(heads[1 + i], -1.f), 1.f);
    float t0 = tanhf(heads[4]), t1 = tanhf(heads[5]);
    float nrm = fmaxf(sqrtf(t0 * t0 + t1 * t1), 1e-6f);
    a[6] = 0.7f * p[6] + 0.3f * t0 / nrm;
    a[7] = 0.7f * p[7] + 0.3f * t1 / nrm;
    a[8] = p[8] + 0.2f * fminf(fmaxf(heads[6], -2.f), 2.f);
    a[9] = p[9] + 0.2f * fminf(fmaxf(heads[7], -2.f), 2.f);
    a[10] = p[10];
    float* oa = out + 102400 + (size_t)(b * 100 + q) * 11;
#pragma unroll
    for (int i = 0; i < 11; ++i) oa[i] = a[i];
    out[106800 + b * 100 + q] = score;
  }
}

extern "C" void kernel_launch(void* const* d_in, const int* in_sizes, int n_in,
                              void* d_out, int out_size, void* d_ws, size_t ws_size,
                              hipStream_t stream) {
  (void)in_sizes; (void)n_in; (void)out_size; (void)ws_size;
  char* ws = (char*)d_ws;
  short* xn     = (short*)(ws + WSO_XN);
  short* featb  = (short*)(ws + WSO_FEATB);
  short* wp1    = (short*)(ws + WSO_WP1);
  short* wp2    = (short*)(ws + WSO_WP2);
  float* bnp    = (float*)(ws + WSO_BNP);
  float* logits = (float*)(ws + WSO_LOG);
  int*   cand   = (int*)(ws + WSO_CAND);
  int*   cnt    = (int*)(ws + WSO_CNT);
  float* exl    = (float*)(ws + WSO_EXL);
  int*   tidx   = (int*)(ws + WSO_TIDX);
  float* tlog   = (float*)(ws + WSO_TLOG);
  float* w1t    = (float*)(ws + WSO_W1T);
  float* w2t    = (float*)(ws + WSO_W2T);

  const float* bev = (const float*)d_in[0];

  wreorder<<<2304, 256, 0, stream>>>((const float*)d_in[2], wp1);
  wreorder<<<2304, 256, 0, stream>>>((const float*)d_in[7], wp2);
  wtrans<<<2304, 256, 0, stream>>>((const float*)d_in[2], w1t);
  wtrans<<<2304, 256, 0, stream>>>((const float*)d_in[7], w2t);
  bnprep<<<1, 256, 0, stream>>>(
      (const float*)d_in[3], (const float*)d_in[4], (const float*)d_in[5],
      (const float*)d_in[6], (const float*)d_in[8], (const float*)d_in[9],
      (const float*)d_in[10], (const float*)d_in[11], (const float*)d_in[12], bnp);
  padzero<<<1024, 256, 0, stream>>>(xn, featb);
  loginit<<<256, 256, 0, stream>>>(logits, (const float*)d_in[13]);
  nchw2nhwc<<<dim3(256, 4, 4), 256, 0, stream>>>(bev, xn);
  conv3x3<0><<<dim3(512, 2), 256, 0, stream>>>(xn, wp1, bnp, bnp + 256,
                                               nullptr, featb, nullptr);
  conv3x3<1><<<dim3(512, 2), 256, 0, stream>>>(featb, wp2, bnp + 512, bnp + 768,
                                               bnp + 1024, nullptr, logits);
  topk_radix<<<4, 1024, 0, stream>>>(logits, cand, cnt);
  rescore<<<dim3(CCAP, 4), 256, 0, stream>>>(bev, w1t, w2t, bnp,
                                             (const float*)d_in[13], cand, cnt,
                                             exl);
  final_topk<<<4, CCAP, 0, stream>>>(exl, cand, cnt, tidx, tlog);
  head_kern<<<400, 256, 0, stream>>>(
      featb, tidx, tlog, (const float*)d_in[1],
      (const float*)d_in[14], (const float*)d_in[15], (const float*)d_in[16],
      (const float*)d_in[17], (const float*)d_in[18], (const float*)d_in[19],
      (const float*)d_in[20], (const float*)d_in[21], (const float*)d_in[22],
      (const float*)d_in[23], (const float*)d_in[24], (const float*)d_in[25],
      (const float*)d_in[26], (const float*)d_in[27], (float*)d_out);
}